// Round 10
// baseline (316.151 us; speedup 1.0000x reference)
//
#include <hip/hip_runtime.h>

#define NB 8
#define NTILE 5440
#define PSTRIDE 772   // 768 ctx + 3 z + 1 pad

typedef float f4 __attribute__((ext_vector_type(4)));

__device__ __forceinline__ f4 ntload(const float* p) {
  return __builtin_nontemporal_load((const f4*)p);
}
__device__ __forceinline__ void ntstore(float* p, f4 v) {
  __builtin_nontemporal_store(v, (f4*)p);
}
__device__ __forceinline__ float hsum(f4 v) { return v.x + v.y + v.z + v.w; }

struct KFArgs {
  const float* x[4];
  float* outp[4];
  float* partial;     // [NTILE][PSTRIDE]
  int N[4];
};

// Fused single-pass: ONE 32-col tile per wg, ONE barrier per wg.
// Thread (oq=tid>>3, snq=tid&7) owns out-rows c2 = oq+64j; the 3 shuffled source
// rows of c2+256k share weight w_qk[c2] and group k. Cross-wg residency (2/CU)
// provides memory/compute overlap instead of in-kernel software pipelining.
__global__ __launch_bounds__(512, 4) void kf_fused(KFArgs a, const float* __restrict__ wqk_all) {
  __shared__ float red[768];   // [wave][k][snq] f4 logit partials
  __shared__ float zl[24];     // [snq][k]

  int wg = blockIdx.x;
  int lvl, b, idx;
  if (wg < 4096)      { lvl = 0; b = wg >> 9;            idx = wg & 511; }
  else if (wg < 5120) { int r = wg - 4096; lvl = 1; b = r >> 7; idx = r & 127; }
  else if (wg < 5376) { int r = wg - 5120; lvl = 2; b = r >> 5; idx = r & 31; }
  else                { int r = wg - 5376; lvl = 3; b = r >> 3; idx = r & 7; }
  int N = a.N[lvl];
  const float* __restrict__ xb = a.x[lvl] + (size_t)b * 768 * N;
  float* __restrict__ outb = a.outp[lvl] + (size_t)b * 256 * N;
  int tid = threadIdx.x;
  int snq = tid & 7, oq = tid >> 3, wv = tid >> 6;
  int n0 = idx * 32 + snq * 4;

  int srow[4][3];
  float wq[4];
#pragma unroll
  for (int j = 0; j < 4; ++j) {
    int c2 = oq + 64 * j;
    wq[j] = wqk_all[lvl * 256 + c2];
#pragma unroll
    for (int k = 0; k < 3; ++k) {
      int f = c2 + (k << 8);
      srow[j][k] = (f % 3) * 256 + f / 3;
    }
  }

  // issue all 12 loads up front (in flight while other resident wg computes)
  f4 X[12];
#pragma unroll
  for (int j = 0; j < 4; ++j)
#pragma unroll
    for (int k = 0; k < 3; ++k)
      X[j * 3 + k] = ntload(xb + (size_t)srow[j][k] * N + n0);

  // logit partials over this thread's 4 channels
  f4 pg[3] = {{0.f, 0.f, 0.f, 0.f}, {0.f, 0.f, 0.f, 0.f}, {0.f, 0.f, 0.f, 0.f}};
#pragma unroll
  for (int j = 0; j < 4; ++j)
#pragma unroll
    for (int k = 0; k < 3; ++k)
      pg[k] += X[j * 3 + k] * wq[j];
  // reduce over the 8 oq-groups within each wave
#pragma unroll
  for (int k = 0; k < 3; ++k) {
#pragma unroll
    for (int m = 8; m <= 32; m <<= 1) {
      pg[k].x += __shfl_xor(pg[k].x, m);
      pg[k].y += __shfl_xor(pg[k].y, m);
      pg[k].z += __shfl_xor(pg[k].z, m);
      pg[k].w += __shfl_xor(pg[k].w, m);
    }
  }
  if ((tid & 63) < 8) {
#pragma unroll
    for (int k = 0; k < 3; ++k)
      *(f4*)(red + (wv * 24 + k * 8 + snq) * 4) = pg[k];
  }
  asm volatile("s_waitcnt lgkmcnt(0)" ::: "memory");
  __builtin_amdgcn_sched_barrier(0);
  __builtin_amdgcn_s_barrier();        // raw barrier: no vmcnt drain
  __builtin_amdgcn_sched_barrier(0);

  // every thread reduces the 8 wave-slices for its 4 cols, all 3 groups
  f4 sev[3];
#pragma unroll
  for (int k = 0; k < 3; ++k) {
    f4 s = {0.f, 0.f, 0.f, 0.f};
#pragma unroll
    for (int w = 0; w < 8; ++w) s += *(const f4*)(red + (w * 24 + k * 8 + snq) * 4);
    f4 e;
    e.x = __expf(s.x); e.y = __expf(s.y); e.z = __expf(s.z); e.w = __expf(s.w);
    sev[k] = e;
  }
  if (tid < 8) {
#pragma unroll
    for (int k = 0; k < 3; ++k) zl[tid * 3 + k] = hsum(sev[k]);
  }

  // out (cached store: L3 retains for K5) + ctx from registers
  float acc[4][3];
#pragma unroll
  for (int j = 0; j < 4; ++j) {
    f4 ov = X[j * 3 + 0] + X[j * 3 + 1] + X[j * 3 + 2];
    *(f4*)(outb + (size_t)(oq + 64 * j) * N + n0) = ov;
#pragma unroll
    for (int k = 0; k < 3; ++k)
      acc[j][k] = hsum(X[j * 3 + k] * sev[k]);
  }

  // reduce ctx over the 8 snq lanes and write per-tile partials
  float* pw = a.partial + (size_t)wg * PSTRIDE;
#pragma unroll
  for (int j = 0; j < 4; ++j)
#pragma unroll
    for (int k = 0; k < 3; ++k) {
      float v = acc[j][k];
      v += __shfl_xor(v, 1);
      v += __shfl_xor(v, 2);
      v += __shfl_xor(v, 4);
      if (snq == 0) pw[k * 256 + oq + 64 * j] = v;
    }
  __syncthreads();
  if (tid < 3) {
    float z = 0.f;
#pragma unroll
    for (int s = 0; s < 8; ++s) z += zl[s * 3 + tid];
    pw[768 + tid] = z;
  }
}

__device__ __forceinline__ float blk_sum256(float v, float* sr4) {
  for (int o = 32; o; o >>= 1) v += __shfl_xor(v, o);
  __syncthreads();
  if ((threadIdx.x & 63) == 0) sr4[threadIdx.x >> 6] = v;
  __syncthreads();
  return sr4[0] + sr4[1] + sr4[2] + sr4[3];
}

// K4: reduce per-tile partials -> ctx (normalized), then ct-MLP + lvl-weight MLP -> add
__global__ __launch_bounds__(256) void k4_mlp(
    const float* __restrict__ partial,
    const float* __restrict__ ct_w1, const float* __restrict__ ct_b1,
    const float* __restrict__ ct_g,  const float* __restrict__ ct_be,
    const float* __restrict__ ct_w2, const float* __restrict__ ct_b2,
    const float* __restrict__ lw_w1, const float* __restrict__ lw_b1,
    const float* __restrict__ lw_g,  const float* __restrict__ lw_be,
    const float* __restrict__ lw_w2, const float* __restrict__ lw_b2,
    float* __restrict__ add_all) {
  int b = blockIdx.x, lvl = blockIdx.y;
  int t = threadIdx.x;
  static const int cnt_[4] = {512, 128, 32, 8};
  static const int base_[4] = {0, 4096, 5120, 5376};
  int cnt = cnt_[lvl];
  int wg0 = base_[lvl] + b * cnt;

  const float* w1 = ct_w1 + lvl * 64 * 256;
  const float* b1 = ct_b1 + lvl * 64;
  const float* cg = ct_g + lvl * 64;
  const float* cbe = ct_be + lvl * 64;
  const float* w2 = ct_w2 + lvl * 256 * 64;
  const float* b2 = ct_b2 + lvl * 256;
  const float* W1 = lw_w1 + (size_t)lvl * 768 * 768;
  const float* B1 = lw_b1 + lvl * 768;
  const float* Lg = lw_g + lvl * 768;
  const float* Lbe = lw_be + lvl * 768;
  const float* W2 = lw_w2 + lvl * 3 * 768;
  const float* B2 = lw_b2 + lvl * 3;
  float* addp = add_all + ((size_t)lvl * NB + b) * 256;

  __shared__ float sctx[768];
  __shared__ float sh1[3][64];
  __shared__ float sl1[768];
  __shared__ float slvlw[3];
  __shared__ float sr4[4];
  __shared__ float sZ[3];
  __shared__ float zp[96];

  // parallel Z reduce (96 threads x strided tiles)
  if (t < 96) {
    int g = t >> 5, j = t & 31;
    float z = 0.f;
    for (int w = j; w < cnt; w += 32)
      z += partial[(size_t)(wg0 + w) * PSTRIDE + 768 + g];
    zp[t] = z;
  }
  // per-column ctx reduce (unrolled for load pipelining)
  float s0 = 0.f, s1 = 0.f, s2 = 0.f;
#pragma unroll 8
  for (int w = 0; w < cnt; ++w) {
    const float* pw = partial + (size_t)(wg0 + w) * PSTRIDE;
    s0 += pw[t];
    s1 += pw[t + 256];
    s2 += pw[t + 512];
  }
  __syncthreads();
  if (t < 3) {
    float z = 0.f;
#pragma unroll
    for (int i = 0; i < 32; ++i) z += zp[t * 32 + i];
    sZ[t] = z;
  }
  __syncthreads();
  sctx[t] = s0 / sZ[0];
  sctx[t + 256] = s1 / sZ[1];
  sctx[t + 512] = s2 / sZ[2];
  __syncthreads();

  if (t < 192) {
    int g = t >> 6, j = t & 63;
    const f4* w4 = (const f4*)(w1 + j * 256);
    const f4* c4 = (const f4*)(sctx + g * 256);
    f4 acc = {0.f, 0.f, 0.f, 0.f};
#pragma unroll 8
    for (int k = 0; k < 64; ++k) acc += c4[k] * w4[k];
    sh1[g][j] = hsum(acc) + b1[j];
  }
  __syncthreads();
  int wv = t >> 6, ln = t & 63;
  if (wv < 3) {
    float v = sh1[wv][ln];
    float s = v;
    for (int o = 32; o; o >>= 1) s += __shfl_xor(s, o);
    float mean = s * (1.f / 64.f);
    float d = v - mean;
    float q = d * d;
    for (int o = 32; o; o >>= 1) q += __shfl_xor(q, o);
    float var = q * (1.f / 64.f);
    float y = d * rsqrtf(var + 1e-5f) * cg[ln] + cbe[ln];
    sh1[wv][ln] = fmaxf(y, 0.f);
  }
  __syncthreads();
  float l1v[3];
#pragma unroll
  for (int r = 0; r < 3; ++r) {
    int j = t + r * 256;
    const f4* W4 = (const f4*)(W1 + (size_t)j * 768);
    const f4* s4 = (const f4*)sctx;
    f4 acc = {0.f, 0.f, 0.f, 0.f};
#pragma unroll 8
    for (int k = 0; k < 192; ++k) acc += s4[k] * W4[k];
    l1v[r] = hsum(acc) + B1[j];
  }
  float S = blk_sum256(l1v[0] + l1v[1] + l1v[2], sr4);
  float mean = S * (1.f / 768.f);
  float q = 0.f;
#pragma unroll
  for (int r = 0; r < 3; ++r) { float d = l1v[r] - mean; q += d * d; }
  float var = blk_sum256(q, sr4) * (1.f / 768.f);
  float inv = rsqrtf(var + 1e-5f);
#pragma unroll
  for (int r = 0; r < 3; ++r) {
    int j = t + r * 256;
    float y = (l1v[r] - mean) * inv * Lg[j] + Lbe[j];
    sl1[j] = fmaxf(y, 0.f);
  }
  __syncthreads();
  if (wv < 3) {
    float acc = 0.f;
    for (int j = ln; j < 768; j += 64) acc = fmaf(sl1[j], W2[wv * 768 + j], acc);
    for (int o = 32; o; o >>= 1) acc += __shfl_xor(acc, o);
    if (ln == 0) slvlw[wv] = 1.f / (1.f + __expf(-(acc + B2[wv])));
  }
  __syncthreads();
  {
    int c2 = t;
    float a = 0.f;
#pragma unroll
    for (int g = 0; g < 3; ++g) {
      const f4* w4 = (const f4*)(w2 + c2 * 64);
      const f4* h4 = (const f4*)(sh1[g]);
      f4 acc = {0.f, 0.f, 0.f, 0.f};
#pragma unroll
      for (int j = 0; j < 16; ++j) acc += h4[j] * w4[j];
      a += (hsum(acc) + b2[c2]) * slvlw[g];
    }
    addp[c2] = a;
  }
}

// K5: out += add (cached read -> L3 hits; nt store) + x_last copy
__global__ __launch_bounds__(256) void k5_add(float* __restrict__ out,
                                              const float* __restrict__ add_all,
                                              const float* __restrict__ xlast) {
  size_t f4i = (size_t)blockIdx.x * 256 + threadIdx.x;
  if (f4i >= 11141120) {
    size_t r = f4i - 11141120;  // < 32768
    f4 v = ntload(xlast + (r << 2));
    ntstore(out + (f4i << 2), v);
    return;
  }
  int lvl, lgN2;
  size_t base;
  if (f4i < 8388608)       { lvl = 0; base = 0;        lgN2 = 12; }
  else if (f4i < 10485760) { lvl = 1; base = 8388608;  lgN2 = 10; }
  else if (f4i < 11010048) { lvl = 2; base = 10485760; lgN2 = 8;  }
  else                     { lvl = 3; base = 11010048; lgN2 = 6;  }
  size_t lf4 = f4i - base;
  int bc = (int)(lf4 >> lgN2);
  float a = add_all[lvl * 2048 + bc];
  float* p = out + (f4i << 2);
  f4 v = *(const f4*)p;
  v += a;
  ntstore(p, v);
}

extern "C" void kernel_launch(void* const* d_in, const int* in_sizes, int n_in,
                              void* d_out, int out_size, void* d_ws, size_t ws_size,
                              hipStream_t stream) {
  const float* gx[4] = {(const float*)d_in[0], (const float*)d_in[1],
                        (const float*)d_in[2], (const float*)d_in[3]};
  const float* x_last = (const float*)d_in[4];
  const float* w_qk = (const float*)d_in[5];
  // d_in[6] = b_qk: constant over softmax axis -> cancels, unused
  const float* ct_w1 = (const float*)d_in[7];
  const float* ct_b1 = (const float*)d_in[8];
  const float* ct_g  = (const float*)d_in[9];
  const float* ct_be = (const float*)d_in[10];
  const float* ct_w2 = (const float*)d_in[11];
  const float* ct_b2 = (const float*)d_in[12];
  const float* lw_w1 = (const float*)d_in[13];
  const float* lw_b1 = (const float*)d_in[14];
  const float* lw_g  = (const float*)d_in[15];
  const float* lw_be = (const float*)d_in[16];
  const float* lw_w2 = (const float*)d_in[17];
  const float* lw_b2 = (const float*)d_in[18];
  float* out = (float*)d_out;
  float* ws = (float*)d_ws;

  static const int Ns[4] = {16384, 4096, 1024, 256};
  static const size_t outOff[4] = {0, 33554432, 41943040, 44040192};

  float* partb = ws;                          // NTILE*PSTRIDE floats (~16.8 MB)
  float* addb  = ws + (size_t)NTILE * PSTRIDE;

  KFArgs af;
  for (int i = 0; i < 4; ++i) {
    af.x[i] = gx[i];
    af.outp[i] = out + outOff[i];
    af.N[i] = Ns[i];
  }
  af.partial = partb;

  kf_fused<<<dim3(NTILE), dim3(512), 0, stream>>>(af, w_qk);
  k4_mlp<<<dim3(NB, 4), dim3(256), 0, stream>>>(partb, ct_w1, ct_b1, ct_g, ct_be,
                                                ct_w2, ct_b2, lw_w1, lw_b1, lw_g,
                                                lw_be, lw_w2, lw_b2, addb);
  k5_add<<<dim3(43648), dim3(256), 0, stream>>>(out, addb, x_last);
}

// Round 11
// 303.526 us; speedup vs baseline: 1.0416x; 1.0416x over previous
//
#include <hip/hip_runtime.h>

#define NB 8
#define NTILE 1360
#define PSTRIDE 772   // 768 ctx + 3 z + 1 pad

typedef float f4 __attribute__((ext_vector_type(4)));

__device__ __forceinline__ f4 ntload(const float* p) {
  return __builtin_nontemporal_load((const f4*)p);
}
__device__ __forceinline__ void ntstore(float* p, f4 v) {
  __builtin_nontemporal_store(v, (f4*)p);
}
__device__ __forceinline__ float hsum(f4 v) { return v.x + v.y + v.z + v.w; }

struct KFArgs {
  const float* x[4];
  float* outp[4];
  float* partial;     // [NTILE][PSTRIDE]
  int N[4];
};

// Fused single-pass, fat tiles: 128 cols x 768 rows per wg, one wg/CU.
// Thread (snq=tid&31, oq=tid>>5) holds X[16][3] f4 (rows src(c2+256k), c2=oq+16j,
// 512B-contiguous per 2 rows per load instr). 48-deep load burst saturates HBM;
// logit: reg FMA + shfl(32) + 12KB LDS cross-wave reduce; out/ctx from registers.
__global__ __launch_bounds__(512, 1) void kf_fused(KFArgs a, const float* __restrict__ wqk_all) {
  __shared__ float red[8 * 3 * 32 * 4];   // [wave][k][quad] f4

  int wg = blockIdx.x;
  int lvl, b, idx;
  if (wg < 1024)      { lvl = 0; b = wg >> 7;            idx = wg & 127; }
  else if (wg < 1280) { int r = wg - 1024; lvl = 1; b = r >> 5; idx = r & 31; }
  else if (wg < 1344) { int r = wg - 1280; lvl = 2; b = r >> 3; idx = r & 7; }
  else                { int r = wg - 1344; lvl = 3; b = r >> 1; idx = r & 1; }
  int N = a.N[lvl];
  const float* __restrict__ xb = a.x[lvl] + (size_t)b * 768 * N;
  float* __restrict__ outb = a.outp[lvl] + (size_t)b * 256 * N;
  int tid = threadIdx.x;
  int snq = tid & 31, oq = tid >> 5, wv = tid >> 6;
  int n0 = idx * 128 + snq * 4;

  float wq[16];
  const float* __restrict__ wqk = wqk_all + lvl * 256;
#pragma unroll
  for (int j = 0; j < 16; ++j) wq[j] = wqk[oq + 16 * j];

  // 48-deep load burst (512B contiguous per 2 rows per instruction)
  f4 X[16][3];
#pragma unroll
  for (int j = 0; j < 16; ++j)
#pragma unroll
    for (int k = 0; k < 3; ++k) {
      int f = oq + 16 * j + 256 * k;
      int row = (f % 3) * 256 + f / 3;
      X[j][k] = ntload(xb + (size_t)row * N + n0);
    }

  // logit partials over this thread's 16 channels
  f4 pg[3] = {{0.f, 0.f, 0.f, 0.f}, {0.f, 0.f, 0.f, 0.f}, {0.f, 0.f, 0.f, 0.f}};
#pragma unroll
  for (int j = 0; j < 16; ++j)
#pragma unroll
    for (int k = 0; k < 3; ++k)
      pg[k] += X[j][k] * wq[j];
  // fold the 2 oq values within each wave (lane bit 5)
#pragma unroll
  for (int k = 0; k < 3; ++k) {
    pg[k].x += __shfl_xor(pg[k].x, 32);
    pg[k].y += __shfl_xor(pg[k].y, 32);
    pg[k].z += __shfl_xor(pg[k].z, 32);
    pg[k].w += __shfl_xor(pg[k].w, 32);
  }
  if ((tid & 32) == 0) {
#pragma unroll
    for (int k = 0; k < 3; ++k)
      *(f4*)(red + ((wv * 3 + k) * 32 + snq) * 4) = pg[k];
  }
  __syncthreads();   // all X loads already consumed; plain barrier is fine

  // every thread sums the 8 wave slices for its quad, all 3 groups -> se
  f4 sev[3];
#pragma unroll
  for (int k = 0; k < 3; ++k) {
    f4 s = {0.f, 0.f, 0.f, 0.f};
#pragma unroll
    for (int w = 0; w < 8; ++w) s += *(const f4*)(red + ((w * 3 + k) * 32 + snq) * 4);
    f4 e;
    e.x = __expf(s.x); e.y = __expf(s.y); e.z = __expf(s.z); e.w = __expf(s.w);
    sev[k] = e;
  }

  float* pw = a.partial + (size_t)wg * PSTRIDE;
  // Z partials: wave 0, lanes 0..31 hold sev for all 32 quads
  if (tid < 32) {
#pragma unroll
    for (int k = 0; k < 3; ++k) {
      float z = hsum(sev[k]);
      z += __shfl_xor(z, 1);
      z += __shfl_xor(z, 2);
      z += __shfl_xor(z, 4);
      z += __shfl_xor(z, 8);
      z += __shfl_xor(z, 16);
      if (tid == 0) pw[768 + k] = z;
    }
  }

  // out (cached store: L3 retains for K5) + ctx from registers
#pragma unroll
  for (int j = 0; j < 16; ++j) {
    int c2 = oq + 16 * j;
    f4 ov = X[j][0] + X[j][1] + X[j][2];
    *(f4*)(outb + (size_t)c2 * N + n0) = ov;
#pragma unroll
    for (int k = 0; k < 3; ++k) {
      float v = hsum(X[j][k] * sev[k]);
      v += __shfl_xor(v, 1);
      v += __shfl_xor(v, 2);
      v += __shfl_xor(v, 4);
      v += __shfl_xor(v, 8);
      v += __shfl_xor(v, 16);
      if (snq == 0) pw[k * 256 + c2] = v;
    }
  }
}

__device__ __forceinline__ float blk_sum256(float v, float* sr4) {
  for (int o = 32; o; o >>= 1) v += __shfl_xor(v, o);
  __syncthreads();
  if ((threadIdx.x & 63) == 0) sr4[threadIdx.x >> 6] = v;
  __syncthreads();
  return sr4[0] + sr4[1] + sr4[2] + sr4[3];
}

// K4: reduce per-tile partials -> ctx (normalized), then ct-MLP + lvl-weight MLP -> add
__global__ __launch_bounds__(256) void k4_mlp(
    const float* __restrict__ partial,
    const float* __restrict__ ct_w1, const float* __restrict__ ct_b1,
    const float* __restrict__ ct_g,  const float* __restrict__ ct_be,
    const float* __restrict__ ct_w2, const float* __restrict__ ct_b2,
    const float* __restrict__ lw_w1, const float* __restrict__ lw_b1,
    const float* __restrict__ lw_g,  const float* __restrict__ lw_be,
    const float* __restrict__ lw_w2, const float* __restrict__ lw_b2,
    float* __restrict__ add_all) {
  int b = blockIdx.x, lvl = blockIdx.y;
  int t = threadIdx.x;
  static const int cnt_[4] = {128, 32, 8, 2};
  static const int base_[4] = {0, 1024, 1280, 1344};
  int cnt = cnt_[lvl];
  int wg0 = base_[lvl] + b * cnt;

  const float* w1 = ct_w1 + lvl * 64 * 256;
  const float* b1 = ct_b1 + lvl * 64;
  const float* cg = ct_g + lvl * 64;
  const float* cbe = ct_be + lvl * 64;
  const float* w2 = ct_w2 + lvl * 256 * 64;
  const float* b2 = ct_b2 + lvl * 256;
  const float* W1 = lw_w1 + (size_t)lvl * 768 * 768;
  const float* B1 = lw_b1 + lvl * 768;
  const float* Lg = lw_g + lvl * 768;
  const float* Lbe = lw_be + lvl * 768;
  const float* W2 = lw_w2 + lvl * 3 * 768;
  const float* B2 = lw_b2 + lvl * 3;
  float* addp = add_all + ((size_t)lvl * NB + b) * 256;

  __shared__ float sctx[768];
  __shared__ float sh1[3][64];
  __shared__ float sl1[768];
  __shared__ float slvlw[3];
  __shared__ float sr4[4];
  __shared__ float sZ[3];
  __shared__ float zp[96];

  if (t < 96) {
    int g = t >> 5, j = t & 31;
    float z = 0.f;
    for (int w = j; w < cnt; w += 32)
      z += partial[(size_t)(wg0 + w) * PSTRIDE + 768 + g];
    zp[t] = z;
  }
  float s0 = 0.f, s1 = 0.f, s2 = 0.f;
#pragma unroll 8
  for (int w = 0; w < cnt; ++w) {
    const float* pw = partial + (size_t)(wg0 + w) * PSTRIDE;
    s0 += pw[t];
    s1 += pw[t + 256];
    s2 += pw[t + 512];
  }
  __syncthreads();
  if (t < 3) {
    float z = 0.f;
#pragma unroll
    for (int i = 0; i < 32; ++i) z += zp[t * 32 + i];
    sZ[t] = z;
  }
  __syncthreads();
  sctx[t] = s0 / sZ[0];
  sctx[t + 256] = s1 / sZ[1];
  sctx[t + 512] = s2 / sZ[2];
  __syncthreads();

  if (t < 192) {
    int g = t >> 6, j = t & 63;
    const f4* w4 = (const f4*)(w1 + j * 256);
    const f4* c4 = (const f4*)(sctx + g * 256);
    f4 acc = {0.f, 0.f, 0.f, 0.f};
#pragma unroll 8
    for (int k = 0; k < 64; ++k) acc += c4[k] * w4[k];
    sh1[g][j] = hsum(acc) + b1[j];
  }
  __syncthreads();
  int wv = t >> 6, ln = t & 63;
  if (wv < 3) {
    float v = sh1[wv][ln];
    float s = v;
    for (int o = 32; o; o >>= 1) s += __shfl_xor(s, o);
    float mean = s * (1.f / 64.f);
    float d = v - mean;
    float q = d * d;
    for (int o = 32; o; o >>= 1) q += __shfl_xor(q, o);
    float var = q * (1.f / 64.f);
    float y = d * rsqrtf(var + 1e-5f) * cg[ln] + cbe[ln];
    sh1[wv][ln] = fmaxf(y, 0.f);
  }
  __syncthreads();
  float l1v[3];
#pragma unroll
  for (int r = 0; r < 3; ++r) {
    int j = t + r * 256;
    const f4* W4 = (const f4*)(W1 + (size_t)j * 768);
    const f4* s4 = (const f4*)sctx;
    f4 acc = {0.f, 0.f, 0.f, 0.f};
#pragma unroll 8
    for (int k = 0; k < 192; ++k) acc += s4[k] * W4[k];
    l1v[r] = hsum(acc) + B1[j];
  }
  float S = blk_sum256(l1v[0] + l1v[1] + l1v[2], sr4);
  float mean = S * (1.f / 768.f);
  float q = 0.f;
#pragma unroll
  for (int r = 0; r < 3; ++r) { float d = l1v[r] - mean; q += d * d; }
  float var = blk_sum256(q, sr4) * (1.f / 768.f);
  float inv = rsqrtf(var + 1e-5f);
#pragma unroll
  for (int r = 0; r < 3; ++r) {
    int j = t + r * 256;
    float y = (l1v[r] - mean) * inv * Lg[j] + Lbe[j];
    sl1[j] = fmaxf(y, 0.f);
  }
  __syncthreads();
  if (wv < 3) {
    float acc = 0.f;
    for (int j = ln; j < 768; j += 64) acc = fmaf(sl1[j], W2[wv * 768 + j], acc);
    for (int o = 32; o; o >>= 1) acc += __shfl_xor(acc, o);
    if (ln == 0) slvlw[wv] = 1.f / (1.f + __expf(-(acc + B2[wv])));
  }
  __syncthreads();
  {
    int c2 = t;
    float a = 0.f;
#pragma unroll
    for (int g = 0; g < 3; ++g) {
      const f4* w4 = (const f4*)(w2 + c2 * 64);
      const f4* h4 = (const f4*)(sh1[g]);
      f4 acc = {0.f, 0.f, 0.f, 0.f};
#pragma unroll
      for (int j = 0; j < 16; ++j) acc += h4[j] * w4[j];
      a += (hsum(acc) + b2[c2]) * slvlw[g];
    }
    addp[c2] = a;
  }
}

// K5: out += add (cached read -> L3 hits; nt store) + x_last copy
__global__ __launch_bounds__(256) void k5_add(float* __restrict__ out,
                                              const float* __restrict__ add_all,
                                              const float* __restrict__ xlast) {
  size_t f4i = (size_t)blockIdx.x * 256 + threadIdx.x;
  if (f4i >= 11141120) {
    size_t r = f4i - 11141120;  // < 32768
    f4 v = ntload(xlast + (r << 2));
    ntstore(out + (f4i << 2), v);
    return;
  }
  int lvl, lgN2;
  size_t base;
  if (f4i < 8388608)       { lvl = 0; base = 0;        lgN2 = 12; }
  else if (f4i < 10485760) { lvl = 1; base = 8388608;  lgN2 = 10; }
  else if (f4i < 11010048) { lvl = 2; base = 10485760; lgN2 = 8;  }
  else                     { lvl = 3; base = 11010048; lgN2 = 6;  }
  size_t lf4 = f4i - base;
  int bc = (int)(lf4 >> lgN2);
  float a = add_all[lvl * 2048 + bc];
  float* p = out + (f4i << 2);
  f4 v = *(const f4*)p;
  v += a;
  ntstore(p, v);
}

extern "C" void kernel_launch(void* const* d_in, const int* in_sizes, int n_in,
                              void* d_out, int out_size, void* d_ws, size_t ws_size,
                              hipStream_t stream) {
  const float* gx[4] = {(const float*)d_in[0], (const float*)d_in[1],
                        (const float*)d_in[2], (const float*)d_in[3]};
  const float* x_last = (const float*)d_in[4];
  const float* w_qk = (const float*)d_in[5];
  // d_in[6] = b_qk: constant over softmax axis -> cancels, unused
  const float* ct_w1 = (const float*)d_in[7];
  const float* ct_b1 = (const float*)d_in[8];
  const float* ct_g  = (const float*)d_in[9];
  const float* ct_be = (const float*)d_in[10];
  const float* ct_w2 = (const float*)d_in[11];
  const float* ct_b2 = (const float*)d_in[12];
  const float* lw_w1 = (const float*)d_in[13];
  const float* lw_b1 = (const float*)d_in[14];
  const float* lw_g  = (const float*)d_in[15];
  const float* lw_be = (const float*)d_in[16];
  const float* lw_w2 = (const float*)d_in[17];
  const float* lw_b2 = (const float*)d_in[18];
  float* out = (float*)d_out;
  float* ws = (float*)d_ws;

  static const int Ns[4] = {16384, 4096, 1024, 256};
  static const size_t outOff[4] = {0, 33554432, 41943040, 44040192};

  float* partb = ws;                          // NTILE*PSTRIDE floats (~4.2 MB)
  float* addb  = ws + (size_t)NTILE * PSTRIDE;

  KFArgs af;
  for (int i = 0; i < 4; ++i) {
    af.x[i] = gx[i];
    af.outp[i] = out + outOff[i];
    af.N[i] = Ns[i];
  }
  af.partial = partb;

  kf_fused<<<dim3(NTILE), dim3(512), 0, stream>>>(af, w_qk);
  k4_mlp<<<dim3(NB, 4), dim3(256), 0, stream>>>(partb, ct_w1, ct_b1, ct_g, ct_be,
                                                ct_w2, ct_b2, lw_w1, lw_b1, lw_g,
                                                lw_be, lw_w2, lw_b2, addb);
  k5_add<<<dim3(43648), dim3(256), 0, stream>>>(out, addb, x_last);
}